// Round 3
// baseline (270.643 us; speedup 1.0000x reference)
//
#include <hip/hip_runtime.h>
#include <hip/hip_bf16.h>

// Problem constants
constexpr int BATCH   = 16;
constexpr int IN_NC   = 64;
constexpr int OUT_NC  = 64;
constexpr int KS      = 3;
constexpr int FC      = 512;
constexpr int GROUPS  = 4;
constexpr int CNN_PARA = IN_NC * OUT_NC * KS * KS + OUT_NC; // 36928
constexpr int PER_G   = CNN_PARA / GROUPS;                  // 9232
constexpr int IN_PER_G = FC / GROUPS;                       // 128
constexpr int H = 128, W = 128;
constexpr int HO = 126, WO = 126;
constexpr int PIX = HO * WO;                                // 15876
constexpr int WCOUNT = IN_NC * OUT_NC * KS * KS;            // 36864
constexpr int HW = H * W;                                   // 16384

typedef __attribute__((ext_vector_type(8))) short short8;
typedef __attribute__((ext_vector_type(4))) float f32x4;

static __device__ __forceinline__ short bf16_bits(float f) {
    __hip_bfloat16 h = __float2bfloat16(f);       // RNE
    union { __hip_bfloat16 h; short s; } u; u.h = h;
    return u.s;
}

// ---------------------------------------------------------------------------
// Layer 1/2: out[b,o] = relu(sum_k in[b,k] * w[o,k] + bias[o]);  one wave per
// output element, coalesced weight-row reads, shuffle reduce.  (f32 exact)
// ---------------------------------------------------------------------------
__global__ __launch_bounds__(256) void mlp_layer(
    const float* __restrict__ in, const float* __restrict__ w,
    const float* __restrict__ bias, float* __restrict__ out)
{
    int gtid = blockIdx.x * blockDim.x + threadIdx.x;
    int wave = gtid >> 6;
    int lane = threadIdx.x & 63;
    if (wave >= BATCH * FC) return;
    int b = wave >> 9;
    int o = wave & (FC - 1);
    const float* in_row = in + b * FC;
    const float* w_row  = w + (size_t)o * FC;
    float acc = 0.f;
#pragma unroll
    for (int i = 0; i < FC / 64; ++i) acc += in_row[lane + i * 64] * w_row[lane + i * 64];
#pragma unroll
    for (int off = 32; off > 0; off >>= 1) acc += __shfl_down(acc, off, 64);
    if (lane == 0) {
        float v = acc + bias[o];
        out[b * FC + o] = v > 0.f ? v : 0.f;
    }
}

// ---------------------------------------------------------------------------
// Grouped FC: wb[b, g*PER_G+j] = relu(sum_i h2[b,g*128+i] * w3[g,j,i] + b3[j])
// w3 (19 MB) read exactly once; h2 staged in LDS (broadcast reads).
// ---------------------------------------------------------------------------
__global__ __launch_bounds__(256) void grouped_fc(
    const float* __restrict__ h2, const float* __restrict__ w3,
    const float* __restrict__ b3, float* __restrict__ wb)
{
    __shared__ float hs[BATCH * FC]; // 32 KiB
    int tid = threadIdx.x;
    for (int i = tid; i < BATCH * FC; i += blockDim.x) hs[i] = h2[i];
    __syncthreads();

    int j = blockIdx.x * blockDim.x + tid;
    if (j >= CNN_PARA) return;
    int g  = j / PER_G;
    int jj = j - g * PER_G;
    const float4* wrow = (const float4*)(w3 + ((size_t)g * PER_G + jj) * IN_PER_G);
    float acc[BATCH];
#pragma unroll
    for (int b = 0; b < BATCH; ++b) acc[b] = 0.f;
    const float* hbase = hs + g * IN_PER_G;
#pragma unroll 4
    for (int i4 = 0; i4 < IN_PER_G / 4; ++i4) {
        float4 wv = wrow[i4];
#pragma unroll
        for (int b = 0; b < BATCH; ++b) {
            const float* hb = hbase + b * FC + i4 * 4;
            acc[b] += wv.x * hb[0] + wv.y * hb[1] + wv.z * hb[2] + wv.w * hb[3];
        }
    }
    float bv = b3[j];
#pragma unroll
    for (int b = 0; b < BATCH; ++b) {
        float v = acc[b] + bv;
        wb[(size_t)b * CNN_PARA + j] = v > 0.f ? v : 0.f;
    }
}

// ---------------------------------------------------------------------------
// wT[b][kykx][oc][ic] (bf16) = wb[b][(oc*64+ic)*9 + kykx]
// Makes MFMA A-fragments single contiguous 16B loads (8 ic per lane).
// ---------------------------------------------------------------------------
__global__ __launch_bounds__(256) void conv_w_transpose(
    const float* __restrict__ wb, __hip_bfloat16* __restrict__ wT)
{
    int idx = blockIdx.x * blockDim.x + threadIdx.x;   // < 16*9*64*64
    if (idx >= BATCH * 9 * 64 * 64) return;
    int b    = idx / (9 * 4096);
    int r    = idx % (9 * 4096);
    int kykx = r >> 12;
    int q    = r & 4095;
    int oc   = q >> 6;
    int ic   = q & 63;
    float v = wb[(size_t)b * CNN_PARA + (oc * 64 + ic) * 9 + kykx];
    union { __hip_bfloat16 h; short s; } u; u.s = bf16_bits(v);
    wT[idx] = u.h;
}

// ---------------------------------------------------------------------------
// xT[b][h][w][ic] (bf16) = x[b][ic][h][w].  One block per (b,h) row; LDS
// transpose so both global read and write are coalesced.
// ---------------------------------------------------------------------------
__global__ __launch_bounds__(256) void conv_x_transpose(
    const float* __restrict__ x, __hip_bfloat16* __restrict__ xT)
{
    __shared__ float lds[64][129];  // +1 pad: write phase reads stride-129
    int blk = blockIdx.x;           // 16*128
    int b = blk >> 7, h = blk & 127;
    int tid = threadIdx.x;

    const float* xrow = x + (size_t)b * IN_NC * HW + (size_t)h * W;
#pragma unroll 8
    for (int it = 0; it < 32; ++it) {
        int ic = it * 2 + (tid >> 7);
        int w  = tid & 127;
        lds[ic][w] = xrow[(size_t)ic * HW + w];
    }
    __syncthreads();

    __hip_bfloat16* dst = xT + ((size_t)(b * 128 + h)) * (128 * 64);
#pragma unroll
    for (int i = 0; i < 4; ++i) {
        int chunk = i * 256 + tid;      // 0..1023, lanes contiguous
        int w = chunk >> 3, oct = chunk & 7;
        short8 v;
#pragma unroll
        for (int j = 0; j < 8; ++j) v[j] = bf16_bits(lds[oct * 8 + j][w]);
        *(short8*)(dst + (size_t)w * 64 + oct * 8) = v;
    }
}

// ---------------------------------------------------------------------------
// Implicit-GEMM conv, mfma_f32_16x16x32_bf16.  Per block: one sample b, one
// output-row pair.  4 waves: wv&1 = oc half (M32), wv>>1 = output row.
// B-frag = ONE 16B coalesced load from xT (8 contiguous ic per lane);
// A-frag = ONE 16B load from wT.  No LDS.  9 taps x 2 K-steps x 8 N-frags.
// Layouts (verified m89/m91): A/B lane l -> elem[(l>>4)*8+j] at row/col l&15;
// C/D: col=l&15, row=(l>>4)*4+reg.
// ---------------------------------------------------------------------------
__global__ __launch_bounds__(256) void conv_mfma(
    const __hip_bfloat16* __restrict__ xT,  // [16][128][128][64] + pad row
    const __hip_bfloat16* __restrict__ wT,  // [16][9][64][64]
    const float* __restrict__ wb,           // bias source
    float* __restrict__ out)                // [1024][126][126]
{
    int blk = blockIdx.x;          // 16 * 63
    int b   = blk / 63;
    int oyp = blk % 63;
    int tid = threadIdx.x;
    int wv = tid >> 6, l = tid & 63;
    int mrow  = wv & 1;            // which 32-oc half
    int nhalf = wv >> 1;           // which output row of the pair
    int row = oyp * 2 + nhalf;     // 0..125
    int l15 = l & 15, l4 = l >> 4;

    f32x4 acc[2][8];
#pragma unroll
    for (int mf = 0; mf < 2; ++mf)
#pragma unroll
        for (int nf = 0; nf < 8; ++nf) acc[mf][nf] = (f32x4)0.f;

#pragma unroll
    for (int kykx = 0; kykx < 9; ++kykx) {
        int ky = kykx / 3, kx = kykx % 3;
        const __hip_bfloat16* wtile = wT + (size_t)(b * 9 + kykx) * 4096;
        const __hip_bfloat16* xbase =
            xT + ((size_t)(b * 128 + row + ky) * 128 + kx) * 64;
#pragma unroll
        for (int ks = 0; ks < 2; ++ks) {
            int ic0 = ks * 32 + l4 * 8;
            short8 a0 = *(const short8*)(wtile + (mrow * 32 + l15) * 64 + ic0);
            short8 a1 = *(const short8*)(wtile + (mrow * 32 + 16 + l15) * 64 + ic0);
#pragma unroll
            for (int nf = 0; nf < 8; ++nf) {
                int ox = nf * 16 + l15;           // 0..127 (126,127 masked at store)
                short8 bf = *(const short8*)(xbase + (size_t)ox * 64 + ic0);
                acc[0][nf] = __builtin_amdgcn_mfma_f32_16x16x32_bf16(a0, bf, acc[0][nf], 0, 0, 0);
                acc[1][nf] = __builtin_amdgcn_mfma_f32_16x16x32_bf16(a1, bf, acc[1][nf], 0, 0, 0);
            }
        }
    }

    // bias + store.  oc = mrow*32 + mf*16 + l4*4 + r ; ox = nf*16 + l15
    float bias[2][4];
#pragma unroll
    for (int mf = 0; mf < 2; ++mf)
#pragma unroll
        for (int r = 0; r < 4; ++r)
            bias[mf][r] = wb[(size_t)b * CNN_PARA + WCOUNT + mrow * 32 + mf * 16 + l4 * 4 + r];

#pragma unroll
    for (int mf = 0; mf < 2; ++mf)
#pragma unroll
        for (int nf = 0; nf < 8; ++nf) {
            int ox = nf * 16 + l15;
            if (ox >= WO) continue;
#pragma unroll
            for (int r = 0; r < 4; ++r) {
                int oc = mrow * 32 + mf * 16 + l4 * 4 + r;
                out[((size_t)(b * 64 + oc)) * PIX + row * WO + ox] = acc[mf][nf][r] + bias[mf][r];
            }
        }
}

// ---------------------------------------------------------------------------
// Fallback f32 direct conv (used only if ws_size is too small for xT/wT).
// ---------------------------------------------------------------------------
__global__ __launch_bounds__(256) void conv_direct(
    const float* __restrict__ x, const float* __restrict__ wb,
    float* __restrict__ out)
{
    constexpr int NBLK = (PIX + 255) / 256;
    __shared__ float wsm[IN_NC * 9];
    __shared__ float bias_s;
    int bid  = blockIdx.x;
    int tile = bid % NBLK;
    int boc  = bid / NBLK;
    int b = boc >> 6, oc = boc & 63;
    int tid = threadIdx.x;
    const float* wsrc = wb + (size_t)b * CNN_PARA + oc * (IN_NC * 9);
    if (tid < IN_NC * 9 / 4) ((float4*)wsm)[tid] = ((const float4*)wsrc)[tid];
    if (tid == 0) bias_s = wb[(size_t)b * CNN_PARA + WCOUNT + oc];
    __syncthreads();
    int p = tile * 256 + tid;
    if (p >= PIX) return;
    int oy = p / WO, ox = p - oy * WO;
    const float* xb = x + (size_t)b * IN_NC * HW + oy * W + ox;
    float acc = bias_s;
    for (int ic = 0; ic < IN_NC; ++ic) {
        const float* xr = xb + ic * HW;
        const float* wr = wsm + ic * 9;
#pragma unroll
        for (int ky = 0; ky < 3; ++ky) {
            acc += xr[ky * W + 0] * wr[ky * 3 + 0];
            acc += xr[ky * W + 1] * wr[ky * 3 + 1];
            acc += xr[ky * W + 2] * wr[ky * 3 + 2];
        }
    }
    out[(size_t)boc * PIX + p] = acc;
}

// ---------------------------------------------------------------------------
extern "C" void kernel_launch(void* const* d_in, const int* in_sizes, int n_in,
                              void* d_out, int out_size, void* d_ws, size_t ws_size,
                              hipStream_t stream) {
    const float* x     = (const float*)d_in[0];
    const float* fc_in = (const float*)d_in[1];
    const float* w1    = (const float*)d_in[2];
    const float* b1    = (const float*)d_in[3];
    const float* w2    = (const float*)d_in[4];
    const float* b2    = (const float*)d_in[5];
    const float* w3    = (const float*)d_in[6];
    const float* b3    = (const float*)d_in[7];
    float* out = (float*)d_out;

    // ws layout (bytes)
    const size_t off_h1 = 0;
    const size_t off_h2 = off_h1 + (size_t)BATCH * FC * 4;          //  32 KiB
    const size_t off_wb = off_h2 + (size_t)BATCH * FC * 4;          //  32 KiB
    const size_t off_wT = off_wb + (size_t)BATCH * CNN_PARA * 4;    // 2.36 MB
    const size_t off_xT = off_wT + (size_t)BATCH * 9 * 4096 * 2;    // 1.18 MB
    const size_t xT_bytes = (size_t)BATCH * 128 * 128 * 64 * 2 + 16384; // pad row
    const size_t need = off_xT + xT_bytes;                          // ~35.5 MiB

    float* h1 = (float*)((char*)d_ws + off_h1);
    float* h2 = (float*)((char*)d_ws + off_h2);
    float* wb = (float*)((char*)d_ws + off_wb);

    mlp_layer<<<2048, 256, 0, stream>>>(fc_in, w1, b1, h1);
    mlp_layer<<<2048, 256, 0, stream>>>(h1, w2, b2, h2);
    grouped_fc<<<(CNN_PARA + 255) / 256, 256, 0, stream>>>(h2, w3, b3, wb);

    if (ws_size >= need) {
        __hip_bfloat16* wT = (__hip_bfloat16*)((char*)d_ws + off_wT);
        __hip_bfloat16* xT = (__hip_bfloat16*)((char*)d_ws + off_xT);
        conv_w_transpose<<<(BATCH * 9 * 4096 + 255) / 256, 256, 0, stream>>>(wb, wT);
        conv_x_transpose<<<BATCH * 128, 256, 0, stream>>>(x, xT);
        conv_mfma<<<BATCH * 63, 256, 0, stream>>>(xT, wT, wb, out);
    } else {
        conv_direct<<<BATCH * OUT_NC * ((PIX + 255) / 256), 256, 0, stream>>>(x, wb, out);
    }
}